// Round 1
// baseline (240.725 us; speedup 1.0000x reference)
//
#include <hip/hip_runtime.h>
#include <math.h>

#define TV 3200          // T*V = 128*25
#define NTV 204800       // N*T*V = 64*3200
#define NB 800           // blocks of 256 covering NTV exactly
constexpr float EPSF = 1e-5f;

// ---- two-stage reduction helper: wave shuffle -> LDS -> per-block partial ----
template<int NS>
__device__ inline void write_partials(float (&vals)[NS], float* __restrict__ out, float* lds){
  int lane = threadIdx.x & 63;
  int wid  = threadIdx.x >> 6;
  #pragma unroll
  for (int s = 0; s < NS; ++s){
    float v = vals[s];
    #pragma unroll
    for (int o = 32; o > 0; o >>= 1) v += __shfl_down(v, o);
    if (lane == 0) lds[s*4 + wid] = v;
  }
  __syncthreads();
  if ((int)threadIdx.x < NS){
    float v = lds[threadIdx.x*4+0] + lds[threadIdx.x*4+1]
            + lds[threadIdx.x*4+2] + lds[threadIdx.x*4+3];
    out[threadIdx.x*NB + blockIdx.x] = v;
  }
}

// ---- K1: v0 = Wv@x+bv, r0 = Wr@x+br, s = mean_c x ; partial stats of r0 ----
__global__ __launch_bounds__(256) void k_proj(const float* __restrict__ x,
    const float* __restrict__ Wv, const float* __restrict__ bv,
    const float* __restrict__ Wr, const float* __restrict__ br,
    float* __restrict__ v0, float* __restrict__ r0, float* __restrict__ s,
    float* __restrict__ pr){
  __shared__ float sWv[512], sWr[512], lds[16*4];
  int tid = threadIdx.x;
  for (int i = tid; i < 512; i += 256){ sWv[i] = Wv[i]; sWr[i] = Wr[i]; }
  __syncthreads();
  int p = blockIdx.x*256 + tid;              // < NTV
  int n = p / TV, tv = p - n*TV;
  const float* xp = x + (size_t)n*64*TV + tv;
  float av[8] = {0,0,0,0,0,0,0,0};
  float ar[8] = {0,0,0,0,0,0,0,0};
  float ssum = 0.f;
  for (int c = 0; c < 64; ++c){
    float xv = xp[(size_t)c*TV];
    ssum += xv;
    #pragma unroll
    for (int r = 0; r < 8; ++r){
      av[r] = fmaf(sWv[r*64+c], xv, av[r]);
      ar[r] = fmaf(sWr[r*64+c], xv, ar[r]);
    }
  }
  s[p] = ssum * 0.015625f;   // /64
  float* v0p = v0 + (size_t)n*8*TV + tv;
  float* r0p = r0 + (size_t)n*8*TV + tv;
  float vals[16];
  #pragma unroll
  for (int r = 0; r < 8; ++r){
    v0p[(size_t)r*TV] = av[r] + bv[r];
    float rr = ar[r] + br[r];
    r0p[(size_t)r*TV] = rr;
    vals[r] = rr; vals[8+r] = rr*rr;
  }
  write_partials<16>(vals, pr, lds);
}

// ---- K2: W2[n,u,t,v] = sum_w tanh( Ww[w*5+u,:] . m + bw[w*5+u] ), m_k = s[n,t+k-2,v] ----
__global__ __launch_bounds__(256) void k_w2(const float* __restrict__ s,
    const float* __restrict__ Ww, const float* __restrict__ bw,
    float* __restrict__ W2){
  __shared__ float sWw[125], sbw[25];
  int tid = threadIdx.x;
  if (tid < 125) sWw[tid] = Ww[tid];
  if (tid < 25)  sbw[tid] = bw[tid];
  __syncthreads();
  int p = blockIdx.x*256 + tid;
  int n = p / TV, tv = p - n*TV;
  int t = tv / 25, v = tv - t*25;
  float m[5];
  #pragma unroll
  for (int k = 0; k < 5; ++k){
    int tt = t + k - 2;
    m[k] = (tt >= 0 && tt < 128) ? s[n*TV + tt*25 + v] : 0.f;
  }
  float w2[5] = {0,0,0,0,0};
  #pragma unroll
  for (int w = 0; w < 5; ++w){
    #pragma unroll
    for (int u = 0; u < 5; ++u){
      int o = w*5 + u;
      float wo = sbw[o];
      #pragma unroll
      for (int k = 0; k < 5; ++k) wo = fmaf(sWw[o*5+k], m[k], wo);
      w2[u] += tanhf(wo);
    }
  }
  float* W2p = W2 + (size_t)n*5*TV + tv;
  #pragma unroll
  for (int u = 0; u < 5; ++u) W2p[(size_t)u*TV] = w2[u];
}

// ---- K3: att[n,r,t,v] = sum_u W2[n,u,t,v] * v0[n,r,t+u-2,v] ; partial stats ----
__global__ __launch_bounds__(256) void k_att(const float* __restrict__ W2,
    const float* __restrict__ v0, float* __restrict__ att, float* __restrict__ patt){
  __shared__ float lds[16*4];
  int tid = threadIdx.x;
  int p = blockIdx.x*256 + tid;
  int n = p / TV, tv = p - n*TV;
  int t = tv / 25, v = tv - t*25;
  float a[8] = {0,0,0,0,0,0,0,0};
  const float* W2p = W2 + (size_t)n*5*TV + tv;
  const float* v0n = v0 + (size_t)n*8*TV;
  #pragma unroll
  for (int u = 0; u < 5; ++u){
    int tt = t + u - 2;
    if (tt >= 0 && tt < 128){
      float wu = W2p[(size_t)u*TV];
      const float* vp = v0n + tt*25 + v;
      #pragma unroll
      for (int r = 0; r < 8; ++r) a[r] = fmaf(wu, vp[(size_t)r*TV], a[r]);
    }
  }
  float* ap = att + (size_t)n*8*TV + tv;
  float vals[16];
  #pragma unroll
  for (int r = 0; r < 8; ++r){
    ap[(size_t)r*TV] = a[r];
    vals[r] = a[r]; vals[8+r] = a[r]*a[r];
  }
  write_partials<16>(vals, patt, lds);
}

// ---- KR1: finalize BN affine coefs for att (g_bn,b_bn) and res (g_r,b_r) ----
// coef layout: a_att[0..7], c_att[8..15], a_r[16..23], c_r[24..31]
__global__ __launch_bounds__(256) void k_bncoef(const float* __restrict__ pr,
    const float* __restrict__ patt,
    const float* __restrict__ g_bn, const float* __restrict__ b_bn,
    const float* __restrict__ g_r, const float* __restrict__ b_r,
    float* __restrict__ coef){
  __shared__ float lds[8];
  int b = blockIdx.x;                 // 0..15
  bool isatt = (b >= 8);
  int r = isatt ? b - 8 : b;
  const float* ps = (isatt ? patt : pr) + r*NB;
  const float* pq = (isatt ? patt : pr) + (8+r)*NB;
  float s1 = 0.f, s2 = 0.f;
  for (int i = threadIdx.x; i < NB; i += 256){ s1 += ps[i]; s2 += pq[i]; }
  int lane = threadIdx.x & 63, wid = threadIdx.x >> 6;
  #pragma unroll
  for (int o = 32; o > 0; o >>= 1){ s1 += __shfl_down(s1, o); s2 += __shfl_down(s2, o); }
  if (lane == 0){ lds[wid] = s1; lds[4+wid] = s2; }
  __syncthreads();
  if (threadIdx.x == 0){
    float sum = lds[0]+lds[1]+lds[2]+lds[3];
    float sq  = lds[4]+lds[5]+lds[6]+lds[7];
    float mu  = sum / (float)NTV;
    float var = sq / (float)NTV - mu*mu;
    float g  = isatt ? g_bn[r] : g_r[r];
    float bb = isatt ? b_bn[r] : b_r[r];
    float a = g * rsqrtf(var + EPSF);
    float c = bb - a*mu;
    int base = isatt ? 0 : 16;
    coef[base + r] = a;
    coef[base + 8 + r] = c;
  }
}

// ---- K5: h = leaky( bn(att) + bn(r0) ) ; partial sums + upper-tri cross moments ----
__global__ __launch_bounds__(256) void k_h(const float* __restrict__ att,
    const float* __restrict__ r0, const float* __restrict__ coef,
    float* __restrict__ h, float* __restrict__ ph){
  __shared__ float lds[44*4];
  __shared__ float sc[32];
  int tid = threadIdx.x;
  if (tid < 32) sc[tid] = coef[tid];
  __syncthreads();
  int p = blockIdx.x*256 + tid;
  int n = p / TV, tv = p - n*TV;
  const float* ap = att + (size_t)n*8*TV + tv;
  const float* rp = r0  + (size_t)n*8*TV + tv;
  float* hp = h + (size_t)n*8*TV + tv;
  float hv[8];
  #pragma unroll
  for (int r = 0; r < 8; ++r){
    float z = sc[r]*ap[(size_t)r*TV] + sc[8+r] + sc[16+r]*rp[(size_t)r*TV] + sc[24+r];
    hv[r] = (z >= 0.f) ? z : 0.1f*z;
    hp[(size_t)r*TV] = hv[r];
  }
  float vals[44];
  #pragma unroll
  for (int r = 0; r < 8; ++r) vals[r] = hv[r];
  int cnt = 8;
  #pragma unroll
  for (int r = 0; r < 8; ++r){
    #pragma unroll
    for (int r2 = r; r2 < 8; ++r2) vals[cnt++] = hv[r]*hv[r2];
  }
  write_partials<44>(vals, ph, lds);
}

// ---- KR2: reduce the 44 h-statistics over 800 block-partials ----
__global__ __launch_bounds__(256) void k_hred(const float* __restrict__ ph,
    float* __restrict__ hstat){
  __shared__ float lds[4];
  int j = blockIdx.x;   // 0..43
  float s1 = 0.f;
  for (int i = threadIdx.x; i < NB; i += 256) s1 += ph[j*NB + i];
  int lane = threadIdx.x & 63, wid = threadIdx.x >> 6;
  #pragma unroll
  for (int o = 32; o > 0; o >>= 1) s1 += __shfl_down(s1, o);
  if (lane == 0) lds[wid] = s1;
  __syncthreads();
  if (threadIdx.x == 0) hstat[j] = lds[0]+lds[1]+lds[2]+lds[3];
}

// ---- K6: analytic BN over y = Wo.h + bo from h moments; fold into Wo', bo' ----
__global__ __launch_bounds__(128) void k_fold(const float* __restrict__ hstat,
    const float* __restrict__ Wo, const float* __restrict__ bo,
    const float* __restrict__ g_o, const float* __restrict__ b_o,
    float* __restrict__ fold, float* __restrict__ bfold){
  __shared__ double muh[8];
  __shared__ double exx[8][8];
  int o = threadIdx.x;   // 0..127
  if (o < 8) muh[o] = (double)hstat[o] / (double)NTV;
  if (o == 0){
    int cnt = 8;
    for (int r = 0; r < 8; ++r)
      for (int r2 = r; r2 < 8; ++r2){
        double e = (double)hstat[cnt++] / (double)NTV;
        exx[r][r2] = e; exx[r2][r] = e;
      }
  }
  __syncthreads();
  double w[8];
  for (int r = 0; r < 8; ++r) w[r] = (double)Wo[o*8+r];
  double bob = (double)bo[o];
  double mu = bob;
  for (int r = 0; r < 8; ++r) mu += w[r]*muh[r];
  double t = 0.0;
  for (int r = 0; r < 8; ++r)
    for (int r2 = 0; r2 < 8; ++r2) t += w[r]*w[r2]*exx[r][r2];
  double ey2 = t + 2.0*bob*(mu - bob) + bob*bob;
  double var = ey2 - mu*mu;
  double a = (double)g_o[o] / sqrt(var + (double)EPSF);
  for (int r = 0; r < 8; ++r) fold[o*8+r] = (float)(a * w[r]);
  bfold[o] = (float)(a * (bob - mu) + (double)b_o[o]);
}

// ---- K7: out[n,o,t,v] = fold[o,:] . h[n,:,t,v] + bfold[o] ----
__global__ __launch_bounds__(256) void k_out(const float* __restrict__ h,
    const float* __restrict__ fold, const float* __restrict__ bfold,
    float* __restrict__ out){
  __shared__ float sW[1024], sB[128];
  int tid = threadIdx.x;
  for (int i = tid; i < 1024; i += 256) sW[i] = fold[i];
  if (tid < 128) sB[tid] = bfold[tid];
  __syncthreads();
  int p = blockIdx.x*256 + tid;
  int n = p / TV, tv = p - n*TV;
  const float* hp = h + (size_t)n*8*TV + tv;
  float hv[8];
  #pragma unroll
  for (int r = 0; r < 8; ++r) hv[r] = hp[(size_t)r*TV];
  float* op = out + (size_t)n*128*TV + tv;
  #pragma unroll 4
  for (int o = 0; o < 128; ++o){
    float y = sB[o];
    #pragma unroll
    for (int r = 0; r < 8; ++r) y = fmaf(sW[o*8+r], hv[r], y);
    op[(size_t)o*TV] = y;
  }
}

extern "C" void kernel_launch(void* const* d_in, const int* in_sizes, int n_in,
                              void* d_out, int out_size, void* d_ws, size_t ws_size,
                              hipStream_t stream){
  const float* x    = (const float*)d_in[0];
  const float* Wv   = (const float*)d_in[1];
  const float* bv   = (const float*)d_in[2];
  const float* Ww   = (const float*)d_in[3];
  const float* bw   = (const float*)d_in[4];
  const float* g_bn = (const float*)d_in[5];
  const float* b_bn = (const float*)d_in[6];
  const float* Wr   = (const float*)d_in[7];
  const float* br   = (const float*)d_in[8];
  const float* g_r  = (const float*)d_in[9];
  const float* b_r  = (const float*)d_in[10];
  const float* Wo   = (const float*)d_in[11];
  const float* bo   = (const float*)d_in[12];
  const float* g_o  = (const float*)d_in[13];
  const float* b_o  = (const float*)d_in[14];

  float* ws = (float*)d_ws;
  size_t off = 0;
  float* v0   = ws + off; off += 1638400;   // (N,8,T,V)
  float* r0   = ws + off; off += 1638400;
  float* s    = ws + off; off += 204800;    // (N,T,V)
  float* W2   = ws + off; off += 1024000;   // (N,5,T,V)
  float* att  = ws + off; off += 1638400;
  float* hbuf = ws + off; off += 1638400;
  float* pr   = ws + off; off += 16*NB;
  float* patt = ws + off; off += 16*NB;
  float* ph   = ws + off; off += 44*NB;
  float* coef = ws + off; off += 32;
  float* hstat= ws + off; off += 44;
  float* fold = ws + off; off += 1024;
  float* bfold= ws + off; off += 128;

  k_proj  <<<NB, 256, 0, stream>>>(x, Wv, bv, Wr, br, v0, r0, s, pr);
  k_w2    <<<NB, 256, 0, stream>>>(s, Ww, bw, W2);
  k_att   <<<NB, 256, 0, stream>>>(W2, v0, att, patt);
  k_bncoef<<<16, 256, 0, stream>>>(pr, patt, g_bn, b_bn, g_r, b_r, coef);
  k_h     <<<NB, 256, 0, stream>>>(att, r0, coef, hbuf, ph);
  k_hred  <<<44, 256, 0, stream>>>(ph, hstat);
  k_fold  <<<1, 128, 0, stream>>>(hstat, Wo, bo, g_o, b_o, fold, bfold);
  k_out   <<<NB, 256, 0, stream>>>(hbuf, fold, bfold, (float*)d_out);
}